// Round 15
// baseline (375.023 us; speedup 1.0000x reference)
//
#include <hip/hip_runtime.h>
#include <hip/hip_bf16.h>
#include <stdint.h>

static constexpr int cN    = 4096;
static constexpr int cHID  = 256;
static constexpr int cTASK = 128;
static constexpr int cL    = 2;
static constexpr float RLN2 = 1.4426950408889634f;   // 1/ln2

typedef short bf16x8 __attribute__((ext_vector_type(8)));
typedef float f32x4  __attribute__((ext_vector_type(4)));

#define MFMA(a, b, c) __builtin_amdgcn_mfma_f32_16x16x32_bf16((a), (b), (c), 0, 0, 0)

static __device__ __forceinline__ uint16_t f2bf(float f) {
    uint32_t u = __float_as_uint(f);
    uint32_t r = (u + 0x7FFFu + ((u >> 16) & 1u)) >> 16;
    return (uint16_t)r;
}
static __device__ __forceinline__ float bf2f(uint16_t h) {
    return __uint_as_float(((uint32_t)h) << 16);
}
static __device__ __forceinline__ bf16x8 ld_frag(const uint16_t* p) {
    return *reinterpret_cast<const bf16x8*>(p);
}
static __device__ __forceinline__ uint32_t pkf16(float a, float b) {
    _Float16 ha = (_Float16)a, hb = (_Float16)b;
    uint16_t ua, ub;
    __builtin_memcpy(&ua, &ha, 2);
    __builtin_memcpy(&ub, &hb, 2);
    return (uint32_t)ua | ((uint32_t)ub << 16);
}
static __device__ __forceinline__ float f16lo(uint32_t v) {
    uint16_t u = (uint16_t)(v & 0xFFFFu); _Float16 h;
    __builtin_memcpy(&h, &u, 2); return (float)h;
}
static __device__ __forceinline__ float f16hi(uint32_t v) {
    uint16_t u = (uint16_t)(v >> 16); _Float16 h;
    __builtin_memcpy(&h, &u, 2); return (float)h;
}
static __device__ __forceinline__ uint32_t spread4(uint32_t x) {
    x = (x | (x << 12)) & 0x000F000Fu;
    x = (x | (x << 6))  & 0x03030303u;
    x = (x | (x << 3))  & 0x11111111u;
    return x;
}
// async global->LDS, 16B per lane; LDS dest is wave-uniform base + lane*16
static __device__ __forceinline__ void gload_lds16(const void* g, void* l) {
    __builtin_amdgcn_global_load_lds((const __attribute__((address_space(1))) void*)g,
                                     (__attribute__((address_space(3))) void*)l, 16, 0, 0);
}

// ---------------- merged prep: casts + weight transposes + wvec + adj bitmask ----------------
static __device__ __forceinline__ void castT_body(const float* __restrict__ S,
                                                  uint16_t* __restrict__ D, int K, int bx,
                                                  uint16_t (*t)[72]) {
    int ntk = K / 64;
    int tk = (bx % ntk) * 64;
    int td = (bx / ntk) * 64;
    int lane = threadIdx.x & 63, w = threadIdx.x >> 6;
    for (int r = w; r < 64; r += 4) t[r][lane] = f2bf(S[(size_t)(tk + r) * 256 + td + lane]);
    __syncthreads();
    for (int r = w; r < 64; r += 4) D[(size_t)(td + r) * K + tk + lane] = t[lane][r];
}

__global__ __launch_bounds__(256) void k_prep(const float* __restrict__ h,
                                              const float* __restrict__ z,
                                              const float* __restrict__ Wp,
                                              const float* __restrict__ Wm,
                                              const float* __restrict__ Wg,
                                              const float* __restrict__ Wq,
                                              const float* __restrict__ bq,
                                              const float* __restrict__ Wk,
                                              const float* __restrict__ bk,
                                              const float* __restrict__ a,
                                              const int* __restrict__ adj,
                                              uint16_t* __restrict__ hin_bf,
                                              uint16_t* __restrict__ z_bf,
                                              uint16_t* __restrict__ WpT,
                                              uint16_t* __restrict__ WmT,
                                              uint16_t* __restrict__ WgT,
                                              float* __restrict__ wqv,
                                              float* __restrict__ wkv,
                                              float* __restrict__ cvec,
                                              uint32_t* __restrict__ maskw,
                                              float* __restrict__ gsum,
                                              uint32_t* __restrict__ donecnt) {
    __shared__ uint16_t sht[64][72];
    __shared__ float shf[2][256];
    int b = blockIdx.x, tid = threadIdx.x;
    if (b == 0) {
        if (tid == 0) gsum[0] = 0.f;
        if (tid < 128) donecnt[tid] = 0;
    }
    if (b < 1024) {                                    // h cast (vec4)
        int idx = b * 256 + tid;
        float4 v = reinterpret_cast<const float4*>(h)[idx];
        ushort4 o; o.x = f2bf(v.x); o.y = f2bf(v.y); o.z = f2bf(v.z); o.w = f2bf(v.w);
        reinterpret_cast<ushort4*>(hin_bf)[idx] = o;
        return;
    }
    b -= 1024;
    if (b < 512) {                                     // z cast (vec4)
        int idx = b * 256 + tid;
        float4 v = reinterpret_cast<const float4*>(z)[idx];
        ushort4 o; o.x = f2bf(v.x); o.y = f2bf(v.y); o.z = f2bf(v.z); o.w = f2bf(v.w);
        reinterpret_cast<ushort4*>(z_bf)[idx] = o;
        return;
    }
    b -= 512;
    if (b < 16) { castT_body(Wp, WpT, 256, b, sht); return; }
    b -= 16;
    if (b < 32) { castT_body(Wm + (b >> 4) * 65536, WmT + (b >> 4) * 65536, 256, b & 15, sht); return; }
    b -= 32;
    if (b < 48) { castT_body(Wg + (b / 24) * 98304, WgT + (b / 24) * 98304, 384, b % 24, sht); return; }
    b -= 48;
    if (b < 16) {   // wvec: l = b>>3, which = (b>>2)&1, q = b&3  (results scaled by 1/ln2)
        int l = b >> 3, which = (b >> 2) & 1, q = b & 3;
        int lane = tid & 63, wid = tid >> 6;
        const float* W    = which ? (Wk + l * 65536) : (Wq + l * 65536);
        const float* avec = a + l * 512 + (which ? 0 : 256);
        float* av = shf[0];
        float* red = shf[1];
        av[tid] = avec[tid];
        __syncthreads();
        float av0 = av[lane], av1 = av[64 + lane], av2 = av[128 + lane], av3 = av[192 + lane];
        float* wv = which ? wkv : wqv;
        for (int dd = 0; dd < 16; ++dd) {
            int d = q * 64 + wid * 16 + dd;
            const float* Wr = W + (size_t)d * 256;
            float s = Wr[lane] * av0 + Wr[64 + lane] * av1 + Wr[128 + lane] * av2 + Wr[192 + lane] * av3;
            for (int off = 32; off; off >>= 1) s += __shfl_down(s, off, 64);
            if (lane == 0) wv[l * 256 + d] = s * RLN2;
        }
        if (q == 0) {
            const float* bias = which ? (bk + l * 256) : (bq + l * 256);
            red[tid] = bias[tid] * av[tid];
            __syncthreads();
            for (int off = 128; off; off >>= 1) {
                if (tid < off) red[tid] += red[tid + off];
                __syncthreads();
            }
            if (tid == 0) cvec[l * 2 + which] = red[0] * RLN2;
        }
        return;
    }
    b -= 16;
    {   // adj -> bitmask: 1024 blocks, 4 rows each
        int wid = tid >> 6, lane = tid & 63;
        int i = b * 4 + wid;
        const int* row = adj + (size_t)i * cN;
        uint32_t* orow = maskw + (size_t)i * 128;
        for (int ch = 0; ch < 16; ++ch) {
            int4 v = reinterpret_cast<const int4*>(row + ch * 256)[lane];
            uint64_t b0 = __ballot(v.x > 0);
            uint64_t b1 = __ballot(v.y > 0);
            uint64_t b2 = __ballot(v.z > 0);
            uint64_t b3 = __ballot(v.w > 0);
            int k = lane & 7;
            uint32_t e0 = spread4((uint32_t)(b0 >> (8 * k)) & 0xFFu);
            uint32_t e1 = spread4((uint32_t)(b1 >> (8 * k)) & 0xFFu);
            uint32_t e2 = spread4((uint32_t)(b2 >> (8 * k)) & 0xFFu);
            uint32_t e3 = spread4((uint32_t)(b3 >> (8 * k)) & 0xFFu);
            if (lane < 8) orow[ch * 8 + k] = e0 | (e1 << 1) | (e2 << 2) | (e3 << 3);
        }
    }
}

// ---------------- merged: mask bit-transpose (blocks 0-255) + initial projection (blocks 256-511) ----------------
__global__ __launch_bounds__(256) void k_pt(const uint32_t* __restrict__ maskw,
                                            uint32_t* __restrict__ maskT,
                                            const uint16_t* __restrict__ hin_bf,
                                            const uint16_t* __restrict__ WpT,
                                            const float* __restrict__ bp,
                                            float* __restrict__ h_f32,
                                            uint16_t* __restrict__ hcur_bf) {
    __shared__ uint32_t ml[256][9];
    int tid = threadIdx.x;
    if (blockIdx.x < 256) {   // ---- bit-transpose ----
        int bi = blockIdx.x & 15, bj = blockIdx.x >> 4;
        int i0 = bi * 256, j0 = bj * 256;
        {
            const uint32_t* src = maskw + (size_t)(i0 + tid) * 128 + bj * 8;
            uint4 a = *reinterpret_cast<const uint4*>(src);
            uint4 b = *reinterpret_cast<const uint4*>(src + 4);
            ml[tid][0] = a.x; ml[tid][1] = a.y; ml[tid][2] = a.z; ml[tid][3] = a.w;
            ml[tid][4] = b.x; ml[tid][5] = b.y; ml[tid][6] = b.z; ml[tid][7] = b.w;
        }
        __syncthreads();
        int lane = tid & 63, wid = tid >> 6;
        int tw = wid * 2 + (lane >> 5);
        int l31 = lane & 31;
        uint32_t ow[8];
#pragma unroll
        for (int ti = 0; ti < 8; ++ti) {
            uint32_t m = ml[ti * 32 + l31][tw];
            uint32_t myw = 0;
#pragma unroll
            for (int c = 0; c < 32; ++c) {
                uint64_t bl = __ballot(((m >> c) & 1) != 0);
                uint32_t v = (lane < 32) ? (uint32_t)bl : (uint32_t)(bl >> 32);
                if (l31 == c) myw = v;
            }
            ow[ti] = myw;
        }
        uint32_t* dst = maskT + (size_t)(j0 + tw * 32 + l31) * 128 + bi * 8;
        *reinterpret_cast<uint4*>(dst)     = make_uint4(ow[0], ow[1], ow[2], ow[3]);
        *reinterpret_cast<uint4*>(dst + 4) = make_uint4(ow[4], ow[5], ow[6], ow[7]);
        return;
    }
    // ---- initial projection: h = hin @ Wp + bp ----
    int bb = blockIdx.x - 256;
    int bx = bb & 63, by = bb >> 6;
    int lane = tid & 63, wid = tid >> 6;
    int wr = wid >> 1, wc = wid & 1;
    int l16 = lane & 15, g = lane >> 4;
    int i0 = bx * 64 + wr * 32, d0 = by * 64 + wc * 32;
    f32x4 acc[2][2] = {};
#pragma unroll
    for (int ks = 0; ks < 8; ++ks) {
        int kb = ks * 32 + g * 8;
        bf16x8 afr[2], bfr[2];
#pragma unroll
        for (int mr = 0; mr < 2; ++mr) afr[mr] = ld_frag(hin_bf + (size_t)(i0 + mr * 16 + l16) * 256 + kb);
#pragma unroll
        for (int nr = 0; nr < 2; ++nr) bfr[nr] = ld_frag(WpT + (size_t)(d0 + nr * 16 + l16) * 256 + kb);
#pragma unroll
        for (int mr = 0; mr < 2; ++mr)
#pragma unroll
            for (int nr = 0; nr < 2; ++nr)
                acc[mr][nr] = MFMA(afr[mr], bfr[nr], acc[mr][nr]);
    }
#pragma unroll
    for (int mr = 0; mr < 2; ++mr)
#pragma unroll
        for (int nr = 0; nr < 2; ++nr) {
            int d = d0 + nr * 16 + l16;
            float bias = bp[d];
#pragma unroll
            for (int r = 0; r < 4; ++r) {
                int i = i0 + mr * 16 + g * 4 + r;
                float v = acc[mr][nr][r] + bias;
                h_f32[(size_t)i * 256 + d] = v;
                hcur_bf[(size_t)i * 256 + d] = f2bf(v);
            }
        }
}

// ---------------- fused message+gate GEMM + kk GEMV + qq partials + gate L1; writes gmT ----------------
__global__ __launch_bounds__(256) void k_msgg(const uint16_t* __restrict__ hcur_bf,
                                              const uint16_t* __restrict__ z_bf,
                                              const uint16_t* __restrict__ WmT,
                                              const uint16_t* __restrict__ WgT,
                                              const float* __restrict__ bm,
                                              const float* __restrict__ bg,
                                              const float* __restrict__ wqv,
                                              const float* __restrict__ wkv,
                                              const float* __restrict__ cvec,
                                              uint16_t* __restrict__ gmT,
                                              float* __restrict__ qqp,
                                              float* __restrict__ kkv,
                                              float* __restrict__ gsum,
                                              int layer) {
    __shared__ float wkv_s[256], wqv_s[256];
    __shared__ float wred[4];
    int tid = threadIdx.x;
    wkv_s[tid] = wkv[layer * 256 + tid];
    wqv_s[tid] = wqv[layer * 256 + tid];
    __syncthreads();

    int bx = blockIdx.x, by = blockIdx.y;
    int lane = tid & 63, wid = tid >> 6;
    int wr = wid >> 1, wc = wid & 1;
    int l16 = lane & 15, g = lane >> 4;
    int i0 = bx * 64 + wr * 32, d0 = by * 64 + wc * 32;
    bool doKK = (by == 0);
    const uint16_t* WmTl = WmT + layer * 65536;
    const uint16_t* WgTl = WgT + layer * 98304;
    f32x4 am[2][2] = {}, ag[2][2] = {};
    float kkp[2] = {0.f, 0.f};
#pragma unroll
    for (int ks = 0; ks < 8; ++ks) {
        int kb = ks * 32 + g * 8;
        bf16x8 afr[2], bmf[2], bgf[2];
#pragma unroll
        for (int mr = 0; mr < 2; ++mr) afr[mr] = ld_frag(hcur_bf + (size_t)(i0 + mr * 16 + l16) * 256 + kb);
#pragma unroll
        for (int nr = 0; nr < 2; ++nr) {
            bmf[nr] = ld_frag(WmTl + (size_t)(d0 + nr * 16 + l16) * 256 + kb);
            bgf[nr] = ld_frag(WgTl + (size_t)(d0 + nr * 16 + l16) * 384 + kb);
        }
        if (doKK) {
#pragma unroll
            for (int mr = 0; mr < 2; ++mr)
#pragma unroll
                for (int u = 0; u < 8; ++u)
                    kkp[mr] += bf2f((uint16_t)afr[mr][u]) * wkv_s[kb + u];
        }
#pragma unroll
        for (int mr = 0; mr < 2; ++mr)
#pragma unroll
            for (int nr = 0; nr < 2; ++nr) {
                am[mr][nr] = MFMA(afr[mr], bmf[nr], am[mr][nr]);
                ag[mr][nr] = MFMA(afr[mr], bgf[nr], ag[mr][nr]);
            }
    }
#pragma unroll
    for (int ks = 0; ks < 4; ++ks) {   // z part of concat: k = 256..383
        int kb = ks * 32 + g * 8;
        bf16x8 afr[2], bgf[2];
#pragma unroll
        for (int mr = 0; mr < 2; ++mr) afr[mr] = ld_frag(z_bf + (size_t)(i0 + mr * 16 + l16) * 128 + kb);
#pragma unroll
        for (int nr = 0; nr < 2; ++nr) bgf[nr] = ld_frag(WgTl + (size_t)(d0 + nr * 16 + l16) * 384 + 256 + kb);
#pragma unroll
        for (int mr = 0; mr < 2; ++mr)
#pragma unroll
            for (int nr = 0; nr < 2; ++nr)
                ag[mr][nr] = MFMA(afr[mr], bgf[nr], ag[mr][nr]);
    }
    float gs = 0.f;
    float qqt[2][4] = {};
#pragma unroll
    for (int mr = 0; mr < 2; ++mr)
#pragma unroll
        for (int nr = 0; nr < 2; ++nr) {
            int d = d0 + nr * 16 + l16;
            float bmv = bm[layer * 256 + d], bgv = bg[layer * 256 + d];
            float wqd = wqv_s[d];
            ushort4 pack;
#pragma unroll
            for (int r = 0; r < 4; ++r) {
                float rm = am[mr][nr][r] + bmv; rm = rm > 0.f ? rm : 0.f;
                float gt = 1.f / (1.f + __expf(-(ag[mr][nr][r] + bgv)));
                gs += gt;
                float gmv = gt * rm;
                qqt[mr][r] += gmv * wqd;
                ((uint16_t*)&pack)[r] = f2bf(gmv);
            }
            int i = i0 + mr * 16 + g * 4;
            *reinterpret_cast<ushort4*>(gmT + (size_t)d * cN + i) = pack;
        }
    // deterministic qq partials: slot = by*2 + wc
#pragma unroll
    for (int mr = 0; mr < 2; ++mr)
#pragma unroll
        for (int r = 0; r < 4; ++r) {
            float v = qqt[mr][r];
            v += __shfl_xor(v, 1, 64);
            v += __shfl_xor(v, 2, 64);
            v += __shfl_xor(v, 4, 64);
            v += __shfl_xor(v, 8, 64);
            if (l16 == 0) qqp[(size_t)(by * 2 + wc) * cN + i0 + mr * 16 + g * 4 + r] = v;
        }
    if (doKK) {
        float cc = cvec[layer * 2 + 0] + cvec[layer * 2 + 1];
#pragma unroll
        for (int mr = 0; mr < 2; ++mr) {
            float v = kkp[mr];
            v += __shfl_xor(v, 16, 64);
            v += __shfl_xor(v, 32, 64);
            if (lane < 16) kkv[i0 + mr * 16 + l16] = v + cc;
        }
    }
    for (int off = 32; off; off >>= 1) gs += __shfl_down(gs, off, 64);
    if (lane == 0) wred[wid] = gs;
    __syncthreads();
    if (tid == 0) atomicAdd(gsum, wred[0] + wred[1] + wred[2] + wred[3]);
}

// ---------------- per-row: qq = sum of 8 partials ; den = sum_masked exp2(lrelu') ----------------
__global__ __launch_bounds__(256) void k_stats(const float* __restrict__ qqp,
                                               const float* __restrict__ kkv,
                                               const uint32_t* __restrict__ maskw,
                                               float2* __restrict__ stats2) {
    int wid = threadIdx.x >> 6, lane = threadIdx.x & 63;
    int i = blockIdx.x * 4 + wid;
    float qq = 0.f;
#pragma unroll
    for (int s = 0; s < 8; ++s) qq += qqp[(size_t)s * cN + i];
    const uint32_t* mrow = maskw + (size_t)i * 128;
    float den = 0.f;
#pragma unroll 4
    for (int c = 0; c < 64; ++c) {
        int j = c * 64 + lane;
        uint32_t w = mrow[j >> 5];
        bool on = (w >> (j & 31)) & 1;
        float e = qq + kkv[j];
        e = fmaxf(e, 0.01f * e);
        e = fminf(e, 80.f);
        den += on ? exp2f(e) : 0.f;
    }
#pragma unroll
    for (int off = 32; off; off >>= 1) den += __shfl_xor(den, off, 64);
    if (lane == 0) stats2[i] = make_float2(qq, den > 0.f ? 1.f / den : 0.f);
}

// ---------------- agg = attention^T @ gm + FUSED residual (last seg-block per jb reduces) ----------------
// grid (64 jb, 8 seg), 512 thr = 8 waves: wave = (jg=wid>>2) 32 j x (dg=wid&3) 64 d.
__global__ __launch_bounds__(512, 4) void k_agg(const uint16_t* __restrict__ gmT,
                                                const float2* __restrict__ stats2,
                                                const uint32_t* __restrict__ maskT,
                                                const float* __restrict__ kkv,
                                                uint32_t* __restrict__ part,
                                                float* __restrict__ h_f32,
                                                uint16_t* __restrict__ hcur_bf,
                                                float* __restrict__ out,
                                                const float* __restrict__ gsum,
                                                uint32_t* __restrict__ donecnt,
                                                int last) {
    __shared__ uint16_t B_lds[2][256 * 64];            // 2 x 32 KiB
    __shared__ uint16_t A_lds[2][64 * 64];             // 2 x 8 KiB
    int jb = blockIdx.x, seg = blockIdx.y;
    int tid = threadIdx.x, lane = tid & 63, wid = tid >> 6;
    int l16 = lane & 15, g = lane >> 4;
    int jg = wid >> 2, dg = wid & 3;
    int jt = jb * 64;
    int ib0 = seg * 512;
    f32x4 acc[2][4] = {};

    // ---- B staging via async global_load_lds (pre-swizzled source, linear LDS dest)
    int io8 = 8 * ((lane & 7) ^ (lane >> 3));
    const uint16_t* gsrc0 = gmT + (size_t)(wid * 32 + (lane >> 3)) * cN + ib0 + io8;
    auto stageB = [&](int buf, int stg) {
        const uint16_t* gs = gsrc0 + stg * 64;
        uint16_t* ldst = &B_lds[buf][(wid * 32) * 64];
#pragma unroll
        for (int c = 0; c < 4; ++c)
            gload_lds16(gs + (size_t)(c * 8) * cN, ldst + (c * 8) * 64);
    };
    // ---- A compute: thread -> j = tid>>3 (0..63), i-octet io = tid&7 (8 i each)
    int at_j = tid >> 3, at_io = tid & 7;
    float kk_t = kkv[jt + at_j];
    const uint32_t* mrow_t = maskT + (size_t)(jt + at_j) * 128;
    int ash = (at_io * 16) ^ ((at_j & 7) << 4);
    uint8_t* arow[2] = { reinterpret_cast<uint8_t*>(&A_lds[0][0]) + at_j * 128 + ash,
                         reinterpret_cast<uint8_t*>(&A_lds[1][0]) + at_j * 128 + ash };
    auto stageA = [&](int buf, int stg) {
        int ib = ib0 + stg * 64 + at_io * 8;
        uint32_t mword = mrow_t[ib >> 5];
        int shift = ib & 31;
        const float2* sp = stats2 + ib;
        union { bf16x8 v; uint16_t s[8]; } aw;
#pragma unroll
        for (int u = 0; u < 8; ++u) {
            float2 st = sp[u];
            float e = st.x + kk_t;
            e = fmaxf(e, 0.01f * e);
            e = fminf(e, 80.f);
            float w = exp2f(e) * st.y;
            aw.s[u] = ((mword >> (shift + u)) & 1) ? f2bf(w) : (uint16_t)0;
        }
        *reinterpret_cast<bf16x8*>(arow[buf]) = aw.v;
    };

    stageB(0, 0);
    stageA(0, 0);
    __syncthreads();
    int rxor = (l16 & 7) << 4;

    for (int stg = 0; stg < 8; ++stg) {
        if (stg < 7) {
            stageB((stg + 1) & 1, stg + 1);
            stageA((stg + 1) & 1, stg + 1);
        }
        const uint8_t* cb = reinterpret_cast<const uint8_t*>(&B_lds[stg & 1][0]);
        const uint8_t* ca = reinterpret_cast<const uint8_t*>(&A_lds[stg & 1][0]);
#pragma unroll
        for (int k = 0; k < 2; ++k) {
            int cofs = (k * 64 + g * 16);
            bf16x8 a0 = *reinterpret_cast<const bf16x8*>(ca + (size_t)(jg * 32 + l16) * 128 + (cofs ^ rxor));
            bf16x8 a1 = *reinterpret_cast<const bf16x8*>(ca + (size_t)(jg * 32 + 16 + l16) * 128 + (cofs ^ rxor));
            const uint8_t* bcol = cb + (size_t)(dg * 64 + l16) * 128 + (cofs ^ rxor);
#pragma unroll
            for (int nf = 0; nf < 4; ++nf) {
                bf16x8 bfr = *reinterpret_cast<const bf16x8*>(bcol + nf * (16 * 128));
                acc[0][nf] = MFMA(a0, bfr, acc[0][nf]);
                acc[1][nf] = MFMA(a1, bfr, acc[1][nf]);
            }
        }
        __syncthreads();
    }
    // coalesced part write: [seg][jb][wid][mf][nf][rr][lane] u32 (f16 pair r=2rr,2rr+1)
    uint32_t* pb = part + ((size_t)(seg * 64 + jb) * 8 + wid) * 1024;
#pragma unroll
    for (int mf = 0; mf < 2; ++mf)
#pragma unroll
        for (int nf = 0; nf < 4; ++nf)
#pragma unroll
            for (int rr = 0; rr < 2; ++rr)
                pb[(((mf * 4 + nf) * 2) + rr) * 64 + lane] =
                    pkf16(acc[mf][nf][rr * 2], acc[mf][nf][rr * 2 + 1]);

    // ---- fused residual: the LAST of the 8 seg-blocks for this jb performs the reduction ----
    __threadfence();                                   // release part writes (device scope)
    __shared__ uint32_t lastFlag;
    if (tid == 0) {
        uint32_t prev = atomicAdd(&donecnt[last * 64 + jb], 1u);
        lastFlag = (prev == 7u) ? 1u : 0u;
    }
    __syncthreads();
    if (!lastFlag) return;
    __threadfence();                                   // acquire: see all seg-blocks' part writes
    if (last && jb == 0 && tid == 0)
        out[(size_t)cN * cHID] = gsum[0] * (1.f / ((float)(cN * cHID) * (float)cL));
#pragma unroll
    for (int wid_r = 0; wid_r < 8; ++wid_r) {
        int jg_r = wid_r >> 2, dg_r = wid_r & 3;
        const uint32_t* pb2 = part + ((size_t)jb * 8 + wid_r) * 1024;
#pragma unroll
        for (int t = 0; t < 2; ++t) {
            int idx = t * 512 + tid;
            float s0 = 0.f, s1 = 0.f;
#pragma unroll
            for (int sg = 0; sg < 8; ++sg) {
                uint32_t v = pb2[(size_t)sg * (64 * 8 * 1024) + idx];
                s0 += f16lo(v); s1 += f16hi(v);
            }
            int mf = idx >> 9, nf = (idx >> 7) & 3, rr = (idx >> 6) & 1, ln = idx & 63;
            int j = jb * 64 + jg_r * 32 + mf * 16 + (ln >> 4) * 4 + rr * 2;
            int d = dg_r * 64 + nf * 16 + (ln & 15);
            size_t p0 = (size_t)j * 256 + d, p1 = p0 + 256;
            float v0 = (s0 + h_f32[p0]) * 0.5f;
            float v1 = (s1 + h_f32[p1]) * 0.5f;
            if (last) {
                out[p0] = v0; out[p1] = v1;
            } else {
                h_f32[p0] = v0; h_f32[p1] = v1;
                hcur_bf[p0] = f2bf(v0); hcur_bf[p1] = f2bf(v1);
            }
        }
    }
}

// ---------------- host side ----------------
extern "C" void kernel_launch(void* const* d_in, const int* in_sizes, int n_in,
                              void* d_out, int out_size, void* d_ws, size_t ws_size,
                              hipStream_t stream) {
    const float* h   = (const float*)d_in[0];
    const int*   adj = (const int*)d_in[1];
    const float* z   = (const float*)d_in[2];
    const float* Wp  = (const float*)d_in[3];
    const float* bp  = (const float*)d_in[4];
    const float* Wm  = (const float*)d_in[5];
    const float* bm  = (const float*)d_in[6];
    const float* Wg  = (const float*)d_in[7];
    const float* bg  = (const float*)d_in[8];
    const float* Wk  = (const float*)d_in[9];
    const float* bk  = (const float*)d_in[10];
    const float* Wq  = (const float*)d_in[11];
    const float* bq  = (const float*)d_in[12];
    const float* a   = (const float*)d_in[13];
    float* out = (float*)d_out;

    uint8_t* ws = (uint8_t*)d_ws;
    size_t cur = 0;
    auto alloc = [&](size_t bytes) -> uint8_t* {
        uint8_t* p = ws + cur;
        cur = (cur + bytes + 255) & ~(size_t)255;
        return p;
    };
    uint32_t* maskw  = (uint32_t*)alloc((size_t)cN * 128 * 4);
    uint32_t* maskT  = (uint32_t*)alloc((size_t)cN * 128 * 4);
    float*    h_f32  = (float*)   alloc((size_t)cN * 256 * 4);
    uint16_t* hin_bf = (uint16_t*)alloc((size_t)cN * 256 * 2);
    uint16_t* hcur   = (uint16_t*)alloc((size_t)cN * 256 * 2);
    uint16_t* z_bf   = (uint16_t*)alloc((size_t)cN * 128 * 2);
    uint16_t* WpT    = (uint16_t*)alloc(65536 * 2);
    uint16_t* WmT    = (uint16_t*)alloc((size_t)cL * 65536 * 2);
    uint16_t* WgT    = (uint16_t*)alloc((size_t)cL * 98304 * 2);
    uint16_t* gmT    = (uint16_t*)alloc((size_t)cN * 256 * 2);
    float*    wqv    = (float*)   alloc(cL * 256 * 4);
    float*    wkv    = (float*)   alloc(cL * 256 * 4);
    float*    cvec   = (float*)   alloc(256);
    float*    qqp    = (float*)   alloc(8ull * cN * 4);
    float*    kk     = (float*)   alloc(cN * 4);
    float2*   stats2 = (float2*)  alloc(cN * 8);
    float*    gsum   = (float*)   alloc(256);
    uint32_t* donecnt= (uint32_t*)alloc(128 * 4);
    uint32_t* part   = (uint32_t*)alloc(8ull * cN * 256 * 2);
    (void)cur;

    // 1024 (h) + 512 (z) + 16 (Wp) + 32 (Wm) + 48 (Wg) + 16 (wvec) + 1024 (bits) = 2672 blocks
    k_prep<<<2672, 256, 0, stream>>>(h, z, Wp, Wm, Wg, Wq, bq, Wk, bk, a, adj,
                                     hin_bf, z_bf, WpT, WmT, WgT, wqv, wkv, cvec, maskw, gsum, donecnt);
    // 256 (bitsT) + 256 (proj) = 512 blocks
    k_pt<<<512, 256, 0, stream>>>(maskw, maskT, hin_bf, WpT, bp, h_f32, hcur);

    for (int l = 0; l < cL; ++l) {
        k_msgg<<<dim3(64, 4), 256, 0, stream>>>(hcur, z_bf, WmT, WgT, bm, bg,
                                                wqv, wkv, cvec, gmT, qqp, kk, gsum, l);
        k_stats<<<cN / 4, 256, 0, stream>>>(qqp, kk, maskw, stats2);
        k_agg<<<dim3(64, 8), 512, 0, stream>>>(gmT, stats2, maskT, kk, part,
                                               h_f32, hcur, out, gsum, donecnt, l == cL - 1 ? 1 : 0);
    }
}

// Round 16
// 365.682 us; speedup vs baseline: 1.0255x; 1.0255x over previous
//
#include <hip/hip_runtime.h>
#include <hip/hip_bf16.h>
#include <stdint.h>

static constexpr int cN    = 4096;
static constexpr int cHID  = 256;
static constexpr int cTASK = 128;
static constexpr int cL    = 2;
static constexpr float RLN2 = 1.4426950408889634f;   // 1/ln2

typedef short bf16x8 __attribute__((ext_vector_type(8)));
typedef float f32x4  __attribute__((ext_vector_type(4)));

#define MFMA(a, b, c) __builtin_amdgcn_mfma_f32_16x16x32_bf16((a), (b), (c), 0, 0, 0)

static __device__ __forceinline__ uint16_t f2bf(float f) {
    uint32_t u = __float_as_uint(f);
    uint32_t r = (u + 0x7FFFu + ((u >> 16) & 1u)) >> 16;
    return (uint16_t)r;
}
static __device__ __forceinline__ float bf2f(uint16_t h) {
    return __uint_as_float(((uint32_t)h) << 16);
}
static __device__ __forceinline__ bf16x8 ld_frag(const uint16_t* p) {
    return *reinterpret_cast<const bf16x8*>(p);
}
static __device__ __forceinline__ uint32_t pkf16(float a, float b) {
    _Float16 ha = (_Float16)a, hb = (_Float16)b;
    uint16_t ua, ub;
    __builtin_memcpy(&ua, &ha, 2);
    __builtin_memcpy(&ub, &hb, 2);
    return (uint32_t)ua | ((uint32_t)ub << 16);
}
static __device__ __forceinline__ float f16lo(uint32_t v) {
    uint16_t u = (uint16_t)(v & 0xFFFFu); _Float16 h;
    __builtin_memcpy(&h, &u, 2); return (float)h;
}
static __device__ __forceinline__ float f16hi(uint32_t v) {
    uint16_t u = (uint16_t)(v >> 16); _Float16 h;
    __builtin_memcpy(&h, &u, 2); return (float)h;
}
static __device__ __forceinline__ uint32_t spread4(uint32_t x) {
    x = (x | (x << 12)) & 0x000F000Fu;
    x = (x | (x << 6))  & 0x03030303u;
    x = (x | (x << 3))  & 0x11111111u;
    return x;
}
// async global->LDS, 16B per lane; LDS dest is wave-uniform base + lane*16
static __device__ __forceinline__ void gload_lds16(const void* g, void* l) {
    __builtin_amdgcn_global_load_lds((const __attribute__((address_space(1))) void*)g,
                                     (__attribute__((address_space(3))) void*)l, 16, 0, 0);
}

// ---------------- merged prep: casts + weight transposes + wvec + adj bitmask ----------------
static __device__ __forceinline__ void castT_body(const float* __restrict__ S,
                                                  uint16_t* __restrict__ D, int K, int bx,
                                                  uint16_t (*t)[72]) {
    int ntk = K / 64;
    int tk = (bx % ntk) * 64;
    int td = (bx / ntk) * 64;
    int lane = threadIdx.x & 63, w = threadIdx.x >> 6;
    for (int r = w; r < 64; r += 4) t[r][lane] = f2bf(S[(size_t)(tk + r) * 256 + td + lane]);
    __syncthreads();
    for (int r = w; r < 64; r += 4) D[(size_t)(td + r) * K + tk + lane] = t[lane][r];
}

__global__ __launch_bounds__(256) void k_prep(const float* __restrict__ h,
                                              const float* __restrict__ z,
                                              const float* __restrict__ Wp,
                                              const float* __restrict__ Wm,
                                              const float* __restrict__ Wg,
                                              const float* __restrict__ Wq,
                                              const float* __restrict__ bq,
                                              const float* __restrict__ Wk,
                                              const float* __restrict__ bk,
                                              const float* __restrict__ a,
                                              const int* __restrict__ adj,
                                              uint16_t* __restrict__ hin_bf,
                                              uint16_t* __restrict__ z_bf,
                                              uint16_t* __restrict__ WpT,
                                              uint16_t* __restrict__ WmT,
                                              uint16_t* __restrict__ WgT,
                                              float* __restrict__ wqv,
                                              float* __restrict__ wkv,
                                              float* __restrict__ cvec,
                                              uint32_t* __restrict__ maskw,
                                              float* __restrict__ gsum,
                                              uint32_t* __restrict__ donecnt) {
    __shared__ uint16_t sht[64][72];
    __shared__ float shf[2][256];
    int b = blockIdx.x, tid = threadIdx.x;
    if (b == 0) {
        if (tid == 0) gsum[0] = 0.f;
        if (tid < 128) donecnt[tid] = 0;
    }
    if (b < 1024) {                                    // h cast (vec4)
        int idx = b * 256 + tid;
        float4 v = reinterpret_cast<const float4*>(h)[idx];
        ushort4 o; o.x = f2bf(v.x); o.y = f2bf(v.y); o.z = f2bf(v.z); o.w = f2bf(v.w);
        reinterpret_cast<ushort4*>(hin_bf)[idx] = o;
        return;
    }
    b -= 1024;
    if (b < 512) {                                     // z cast (vec4)
        int idx = b * 256 + tid;
        float4 v = reinterpret_cast<const float4*>(z)[idx];
        ushort4 o; o.x = f2bf(v.x); o.y = f2bf(v.y); o.z = f2bf(v.z); o.w = f2bf(v.w);
        reinterpret_cast<ushort4*>(z_bf)[idx] = o;
        return;
    }
    b -= 512;
    if (b < 16) { castT_body(Wp, WpT, 256, b, sht); return; }
    b -= 16;
    if (b < 32) { castT_body(Wm + (b >> 4) * 65536, WmT + (b >> 4) * 65536, 256, b & 15, sht); return; }
    b -= 32;
    if (b < 48) { castT_body(Wg + (b / 24) * 98304, WgT + (b / 24) * 98304, 384, b % 24, sht); return; }
    b -= 48;
    if (b < 16) {   // wvec: l = b>>3, which = (b>>2)&1, q = b&3  (results scaled by 1/ln2)
        int l = b >> 3, which = (b >> 2) & 1, q = b & 3;
        int lane = tid & 63, wid = tid >> 6;
        const float* W    = which ? (Wk + l * 65536) : (Wq + l * 65536);
        const float* avec = a + l * 512 + (which ? 0 : 256);
        float* av = shf[0];
        float* red = shf[1];
        av[tid] = avec[tid];
        __syncthreads();
        float av0 = av[lane], av1 = av[64 + lane], av2 = av[128 + lane], av3 = av[192 + lane];
        float* wv = which ? wkv : wqv;
        for (int dd = 0; dd < 16; ++dd) {
            int d = q * 64 + wid * 16 + dd;
            const float* Wr = W + (size_t)d * 256;
            float s = Wr[lane] * av0 + Wr[64 + lane] * av1 + Wr[128 + lane] * av2 + Wr[192 + lane] * av3;
            for (int off = 32; off; off >>= 1) s += __shfl_down(s, off, 64);
            if (lane == 0) wv[l * 256 + d] = s * RLN2;
        }
        if (q == 0) {
            const float* bias = which ? (bk + l * 256) : (bq + l * 256);
            red[tid] = bias[tid] * av[tid];
            __syncthreads();
            for (int off = 128; off; off >>= 1) {
                if (tid < off) red[tid] += red[tid + off];
                __syncthreads();
            }
            if (tid == 0) cvec[l * 2 + which] = red[0] * RLN2;
        }
        return;
    }
    b -= 16;
    {   // adj -> bitmask: 1024 blocks, 4 rows each
        int wid = tid >> 6, lane = tid & 63;
        int i = b * 4 + wid;
        const int* row = adj + (size_t)i * cN;
        uint32_t* orow = maskw + (size_t)i * 128;
        for (int ch = 0; ch < 16; ++ch) {
            int4 v = reinterpret_cast<const int4*>(row + ch * 256)[lane];
            uint64_t b0 = __ballot(v.x > 0);
            uint64_t b1 = __ballot(v.y > 0);
            uint64_t b2 = __ballot(v.z > 0);
            uint64_t b3 = __ballot(v.w > 0);
            int k = lane & 7;
            uint32_t e0 = spread4((uint32_t)(b0 >> (8 * k)) & 0xFFu);
            uint32_t e1 = spread4((uint32_t)(b1 >> (8 * k)) & 0xFFu);
            uint32_t e2 = spread4((uint32_t)(b2 >> (8 * k)) & 0xFFu);
            uint32_t e3 = spread4((uint32_t)(b3 >> (8 * k)) & 0xFFu);
            if (lane < 8) orow[ch * 8 + k] = e0 | (e1 << 1) | (e2 << 2) | (e3 << 3);
        }
    }
}

// ---------------- merged: mask bit-transpose (blocks 0-255) + initial projection (blocks 256-511) ----------------
__global__ __launch_bounds__(256) void k_pt(const uint32_t* __restrict__ maskw,
                                            uint32_t* __restrict__ maskT,
                                            const uint16_t* __restrict__ hin_bf,
                                            const uint16_t* __restrict__ WpT,
                                            const float* __restrict__ bp,
                                            float* __restrict__ h_f32,
                                            uint16_t* __restrict__ hcur_bf) {
    __shared__ uint32_t ml[256][9];
    int tid = threadIdx.x;
    if (blockIdx.x < 256) {   // ---- bit-transpose ----
        int bi = blockIdx.x & 15, bj = blockIdx.x >> 4;
        int i0 = bi * 256, j0 = bj * 256;
        {
            const uint32_t* src = maskw + (size_t)(i0 + tid) * 128 + bj * 8;
            uint4 a = *reinterpret_cast<const uint4*>(src);
            uint4 b = *reinterpret_cast<const uint4*>(src + 4);
            ml[tid][0] = a.x; ml[tid][1] = a.y; ml[tid][2] = a.z; ml[tid][3] = a.w;
            ml[tid][4] = b.x; ml[tid][5] = b.y; ml[tid][6] = b.z; ml[tid][7] = b.w;
        }
        __syncthreads();
        int lane = tid & 63, wid = tid >> 6;
        int tw = wid * 2 + (lane >> 5);
        int l31 = lane & 31;
        uint32_t ow[8];
#pragma unroll
        for (int ti = 0; ti < 8; ++ti) {
            uint32_t m = ml[ti * 32 + l31][tw];
            uint32_t myw = 0;
#pragma unroll
            for (int c = 0; c < 32; ++c) {
                uint64_t bl = __ballot(((m >> c) & 1) != 0);
                uint32_t v = (lane < 32) ? (uint32_t)bl : (uint32_t)(bl >> 32);
                if (l31 == c) myw = v;
            }
            ow[ti] = myw;
        }
        uint32_t* dst = maskT + (size_t)(j0 + tw * 32 + l31) * 128 + bi * 8;
        *reinterpret_cast<uint4*>(dst)     = make_uint4(ow[0], ow[1], ow[2], ow[3]);
        *reinterpret_cast<uint4*>(dst + 4) = make_uint4(ow[4], ow[5], ow[6], ow[7]);
        return;
    }
    // ---- initial projection: h = hin @ Wp + bp ----
    int bb = blockIdx.x - 256;
    int bx = bb & 63, by = bb >> 6;
    int lane = tid & 63, wid = tid >> 6;
    int wr = wid >> 1, wc = wid & 1;
    int l16 = lane & 15, g = lane >> 4;
    int i0 = bx * 64 + wr * 32, d0 = by * 64 + wc * 32;
    f32x4 acc[2][2] = {};
#pragma unroll
    for (int ks = 0; ks < 8; ++ks) {
        int kb = ks * 32 + g * 8;
        bf16x8 afr[2], bfr[2];
#pragma unroll
        for (int mr = 0; mr < 2; ++mr) afr[mr] = ld_frag(hin_bf + (size_t)(i0 + mr * 16 + l16) * 256 + kb);
#pragma unroll
        for (int nr = 0; nr < 2; ++nr) bfr[nr] = ld_frag(WpT + (size_t)(d0 + nr * 16 + l16) * 256 + kb);
#pragma unroll
        for (int mr = 0; mr < 2; ++mr)
#pragma unroll
            for (int nr = 0; nr < 2; ++nr)
                acc[mr][nr] = MFMA(afr[mr], bfr[nr], acc[mr][nr]);
    }
#pragma unroll
    for (int mr = 0; mr < 2; ++mr)
#pragma unroll
        for (int nr = 0; nr < 2; ++nr) {
            int d = d0 + nr * 16 + l16;
            float bias = bp[d];
#pragma unroll
            for (int r = 0; r < 4; ++r) {
                int i = i0 + mr * 16 + g * 4 + r;
                float v = acc[mr][nr][r] + bias;
                h_f32[(size_t)i * 256 + d] = v;
                hcur_bf[(size_t)i * 256 + d] = f2bf(v);
            }
        }
}

// ---------------- fused message+gate GEMM + kk GEMV + qq partials + gate L1; writes gmT ----------------
__global__ __launch_bounds__(256) void k_msgg(const uint16_t* __restrict__ hcur_bf,
                                              const uint16_t* __restrict__ z_bf,
                                              const uint16_t* __restrict__ WmT,
                                              const uint16_t* __restrict__ WgT,
                                              const float* __restrict__ bm,
                                              const float* __restrict__ bg,
                                              const float* __restrict__ wqv,
                                              const float* __restrict__ wkv,
                                              const float* __restrict__ cvec,
                                              uint16_t* __restrict__ gmT,
                                              float* __restrict__ qqp,
                                              float* __restrict__ kkv,
                                              float* __restrict__ gsum,
                                              int layer) {
    __shared__ float wkv_s[256], wqv_s[256];
    __shared__ float wred[4];
    int tid = threadIdx.x;
    wkv_s[tid] = wkv[layer * 256 + tid];
    wqv_s[tid] = wqv[layer * 256 + tid];
    __syncthreads();

    int bx = blockIdx.x, by = blockIdx.y;
    int lane = tid & 63, wid = tid >> 6;
    int wr = wid >> 1, wc = wid & 1;
    int l16 = lane & 15, g = lane >> 4;
    int i0 = bx * 64 + wr * 32, d0 = by * 64 + wc * 32;
    bool doKK = (by == 0);
    const uint16_t* WmTl = WmT + layer * 65536;
    const uint16_t* WgTl = WgT + layer * 98304;
    f32x4 am[2][2] = {}, ag[2][2] = {};
    float kkp[2] = {0.f, 0.f};
#pragma unroll
    for (int ks = 0; ks < 8; ++ks) {
        int kb = ks * 32 + g * 8;
        bf16x8 afr[2], bmf[2], bgf[2];
#pragma unroll
        for (int mr = 0; mr < 2; ++mr) afr[mr] = ld_frag(hcur_bf + (size_t)(i0 + mr * 16 + l16) * 256 + kb);
#pragma unroll
        for (int nr = 0; nr < 2; ++nr) {
            bmf[nr] = ld_frag(WmTl + (size_t)(d0 + nr * 16 + l16) * 256 + kb);
            bgf[nr] = ld_frag(WgTl + (size_t)(d0 + nr * 16 + l16) * 384 + kb);
        }
        if (doKK) {
#pragma unroll
            for (int mr = 0; mr < 2; ++mr)
#pragma unroll
                for (int u = 0; u < 8; ++u)
                    kkp[mr] += bf2f((uint16_t)afr[mr][u]) * wkv_s[kb + u];
        }
#pragma unroll
        for (int mr = 0; mr < 2; ++mr)
#pragma unroll
            for (int nr = 0; nr < 2; ++nr) {
                am[mr][nr] = MFMA(afr[mr], bmf[nr], am[mr][nr]);
                ag[mr][nr] = MFMA(afr[mr], bgf[nr], ag[mr][nr]);
            }
    }
#pragma unroll
    for (int ks = 0; ks < 4; ++ks) {   // z part of concat: k = 256..383
        int kb = ks * 32 + g * 8;
        bf16x8 afr[2], bgf[2];
#pragma unroll
        for (int mr = 0; mr < 2; ++mr) afr[mr] = ld_frag(z_bf + (size_t)(i0 + mr * 16 + l16) * 128 + kb);
#pragma unroll
        for (int nr = 0; nr < 2; ++nr) bgf[nr] = ld_frag(WgTl + (size_t)(d0 + nr * 16 + l16) * 384 + 256 + kb);
#pragma unroll
        for (int mr = 0; mr < 2; ++mr)
#pragma unroll
            for (int nr = 0; nr < 2; ++nr)
                ag[mr][nr] = MFMA(afr[mr], bgf[nr], ag[mr][nr]);
    }
    float gs = 0.f;
    float qqt[2][4] = {};
#pragma unroll
    for (int mr = 0; mr < 2; ++mr)
#pragma unroll
        for (int nr = 0; nr < 2; ++nr) {
            int d = d0 + nr * 16 + l16;
            float bmv = bm[layer * 256 + d], bgv = bg[layer * 256 + d];
            float wqd = wqv_s[d];
            ushort4 pack;
#pragma unroll
            for (int r = 0; r < 4; ++r) {
                float rm = am[mr][nr][r] + bmv; rm = rm > 0.f ? rm : 0.f;
                float gt = 1.f / (1.f + __expf(-(ag[mr][nr][r] + bgv)));
                gs += gt;
                float gmv = gt * rm;
                qqt[mr][r] += gmv * wqd;
                ((uint16_t*)&pack)[r] = f2bf(gmv);
            }
            int i = i0 + mr * 16 + g * 4;
            *reinterpret_cast<ushort4*>(gmT + (size_t)d * cN + i) = pack;
        }
    // deterministic qq partials: slot = by*2 + wc
#pragma unroll
    for (int mr = 0; mr < 2; ++mr)
#pragma unroll
        for (int r = 0; r < 4; ++r) {
            float v = qqt[mr][r];
            v += __shfl_xor(v, 1, 64);
            v += __shfl_xor(v, 2, 64);
            v += __shfl_xor(v, 4, 64);
            v += __shfl_xor(v, 8, 64);
            if (l16 == 0) qqp[(size_t)(by * 2 + wc) * cN + i0 + mr * 16 + g * 4 + r] = v;
        }
    if (doKK) {
        float cc = cvec[layer * 2 + 0] + cvec[layer * 2 + 1];
#pragma unroll
        for (int mr = 0; mr < 2; ++mr) {
            float v = kkp[mr];
            v += __shfl_xor(v, 16, 64);
            v += __shfl_xor(v, 32, 64);
            if (lane < 16) kkv[i0 + mr * 16 + l16] = v + cc;
        }
    }
    for (int off = 32; off; off >>= 1) gs += __shfl_down(gs, off, 64);
    if (lane == 0) wred[wid] = gs;
    __syncthreads();
    if (tid == 0) atomicAdd(gsum, wred[0] + wred[1] + wred[2] + wred[3]);
}

// ---------------- per-row: qq = sum of 8 partials ; den = sum_masked exp2(lrelu') ----------------
__global__ __launch_bounds__(256) void k_stats(const float* __restrict__ qqp,
                                               const float* __restrict__ kkv,
                                               const uint32_t* __restrict__ maskw,
                                               float2* __restrict__ stats2) {
    int wid = threadIdx.x >> 6, lane = threadIdx.x & 63;
    int i = blockIdx.x * 4 + wid;
    float qq = 0.f;
#pragma unroll
    for (int s = 0; s < 8; ++s) qq += qqp[(size_t)s * cN + i];
    const uint32_t* mrow = maskw + (size_t)i * 128;
    float den = 0.f;
#pragma unroll 4
    for (int c = 0; c < 64; ++c) {
        int j = c * 64 + lane;
        uint32_t w = mrow[j >> 5];
        bool on = (w >> (j & 31)) & 1;
        float e = qq + kkv[j];
        e = fmaxf(e, 0.01f * e);
        e = fminf(e, 80.f);
        den += on ? exp2f(e) : 0.f;
    }
#pragma unroll
    for (int off = 32; off; off >>= 1) den += __shfl_xor(den, off, 64);
    if (lane == 0) stats2[i] = make_float2(qq, den > 0.f ? 1.f / den : 0.f);
}

// ---------------- agg = attention^T @ gm + FUSED residual; flag reuses A_lds (LDS stays 80 KiB) ----------------
// grid (64 jb, 8 seg), 512 thr = 8 waves: wave = (jg=wid>>2) 32 j x (dg=wid&3) 64 d.
__global__ __launch_bounds__(512, 4) void k_agg(const uint16_t* __restrict__ gmT,
                                                const float2* __restrict__ stats2,
                                                const uint32_t* __restrict__ maskT,
                                                const float* __restrict__ kkv,
                                                uint32_t* __restrict__ part,
                                                float* __restrict__ h_f32,
                                                uint16_t* __restrict__ hcur_bf,
                                                float* __restrict__ out,
                                                const float* __restrict__ gsum,
                                                uint32_t* __restrict__ donecnt,
                                                int last) {
    __shared__ uint16_t B_lds[2][256 * 64];            // 2 x 32 KiB
    __shared__ uint16_t A_lds[2][64 * 64];             // 2 x 8 KiB  (total exactly 80 KiB)
    int jb = blockIdx.x, seg = blockIdx.y;
    int tid = threadIdx.x, lane = tid & 63, wid = tid >> 6;
    int l16 = lane & 15, g = lane >> 4;
    int jg = wid >> 2, dg = wid & 3;
    int jt = jb * 64;
    int ib0 = seg * 512;
    f32x4 acc[2][4] = {};

    // ---- B staging via async global_load_lds (pre-swizzled source, linear LDS dest)
    int io8 = 8 * ((lane & 7) ^ (lane >> 3));
    const uint16_t* gsrc0 = gmT + (size_t)(wid * 32 + (lane >> 3)) * cN + ib0 + io8;
    auto stageB = [&](int buf, int stg) {
        const uint16_t* gs = gsrc0 + stg * 64;
        uint16_t* ldst = &B_lds[buf][(wid * 32) * 64];
#pragma unroll
        for (int c = 0; c < 4; ++c)
            gload_lds16(gs + (size_t)(c * 8) * cN, ldst + (c * 8) * 64);
    };
    // ---- A compute: thread -> j = tid>>3 (0..63), i-octet io = tid&7 (8 i each)
    int at_j = tid >> 3, at_io = tid & 7;
    float kk_t = kkv[jt + at_j];
    const uint32_t* mrow_t = maskT + (size_t)(jt + at_j) * 128;
    int ash = (at_io * 16) ^ ((at_j & 7) << 4);
    uint8_t* arow[2] = { reinterpret_cast<uint8_t*>(&A_lds[0][0]) + at_j * 128 + ash,
                         reinterpret_cast<uint8_t*>(&A_lds[1][0]) + at_j * 128 + ash };
    auto stageA = [&](int buf, int stg) {
        int ib = ib0 + stg * 64 + at_io * 8;
        uint32_t mword = mrow_t[ib >> 5];
        int shift = ib & 31;
        const float2* sp = stats2 + ib;
        union { bf16x8 v; uint16_t s[8]; } aw;
#pragma unroll
        for (int u = 0; u < 8; ++u) {
            float2 st = sp[u];
            float e = st.x + kk_t;
            e = fmaxf(e, 0.01f * e);
            e = fminf(e, 80.f);
            float w = exp2f(e) * st.y;
            aw.s[u] = ((mword >> (shift + u)) & 1) ? f2bf(w) : (uint16_t)0;
        }
        *reinterpret_cast<bf16x8*>(arow[buf]) = aw.v;
    };

    stageB(0, 0);
    stageA(0, 0);
    __syncthreads();
    int rxor = (l16 & 7) << 4;

    for (int stg = 0; stg < 8; ++stg) {
        if (stg < 7) {
            stageB((stg + 1) & 1, stg + 1);
            stageA((stg + 1) & 1, stg + 1);
        }
        const uint8_t* cb = reinterpret_cast<const uint8_t*>(&B_lds[stg & 1][0]);
        const uint8_t* ca = reinterpret_cast<const uint8_t*>(&A_lds[stg & 1][0]);
#pragma unroll
        for (int k = 0; k < 2; ++k) {
            int cofs = (k * 64 + g * 16);
            bf16x8 a0 = *reinterpret_cast<const bf16x8*>(ca + (size_t)(jg * 32 + l16) * 128 + (cofs ^ rxor));
            bf16x8 a1 = *reinterpret_cast<const bf16x8*>(ca + (size_t)(jg * 32 + 16 + l16) * 128 + (cofs ^ rxor));
            const uint8_t* bcol = cb + (size_t)(dg * 64 + l16) * 128 + (cofs ^ rxor);
#pragma unroll
            for (int nf = 0; nf < 4; ++nf) {
                bf16x8 bfr = *reinterpret_cast<const bf16x8*>(bcol + nf * (16 * 128));
                acc[0][nf] = MFMA(a0, bfr, acc[0][nf]);
                acc[1][nf] = MFMA(a1, bfr, acc[1][nf]);
            }
        }
        __syncthreads();                               // after final iter: all LDS reads complete
    }
    // coalesced part write: [seg][jb][wid][mf][nf][rr][lane] u32 (f16 pair r=2rr,2rr+1)
    uint32_t* pb = part + ((size_t)(seg * 64 + jb) * 8 + wid) * 1024;
#pragma unroll
    for (int mf = 0; mf < 2; ++mf)
#pragma unroll
        for (int nf = 0; nf < 4; ++nf)
#pragma unroll
            for (int rr = 0; rr < 2; ++rr)
                pb[(((mf * 4 + nf) * 2) + rr) * 64 + lane] =
                    pkf16(acc[mf][nf][rr * 2], acc[mf][nf][rr * 2 + 1]);

    // ---- fused residual: last of the 8 seg-blocks for this jb reduces. Flag reuses A_lds (dead now).
    volatile uint32_t* flagp = reinterpret_cast<volatile uint32_t*>(&A_lds[0][0]);
    __threadfence();                                   // release part writes (device scope)
    if (tid == 0) {
        uint32_t prev = atomicAdd(&donecnt[last * 64 + jb], 1u);
        *flagp = (prev == 7u) ? 1u : 0u;
    }
    __syncthreads();
    if (!*flagp) return;
    __threadfence();                                   // acquire: see all seg-blocks' part writes
    if (last && jb == 0 && tid == 0)
        out[(size_t)cN * cHID] = gsum[0] * (1.f / ((float)(cN * cHID) * (float)cL));
#pragma unroll
    for (int wid_r = 0; wid_r < 8; ++wid_r) {
        int jg_r = wid_r >> 2, dg_r = wid_r & 3;
        const uint32_t* pb2 = part + ((size_t)jb * 8 + wid_r) * 1024;
#pragma unroll
        for (int t = 0; t < 2; ++t) {
            int idx = t * 512 + tid;
            float s0 = 0.f, s1 = 0.f;
#pragma unroll
            for (int sg = 0; sg < 8; ++sg) {
                uint32_t v = pb2[(size_t)sg * (64 * 8 * 1024) + idx];
                s0 += f16lo(v); s1 += f16hi(v);
            }
            int mf = idx >> 9, nf = (idx >> 7) & 3, rr = (idx >> 6) & 1, ln = idx & 63;
            int j = jb * 64 + jg_r * 32 + mf * 16 + (ln >> 4) * 4 + rr * 2;
            int d = dg_r * 64 + nf * 16 + (ln & 15);
            size_t p0 = (size_t)j * 256 + d, p1 = p0 + 256;
            float v0 = (s0 + h_f32[p0]) * 0.5f;
            float v1 = (s1 + h_f32[p1]) * 0.5f;
            if (last) {
                out[p0] = v0; out[p1] = v1;
            } else {
                h_f32[p0] = v0; h_f32[p1] = v1;
                hcur_bf[p0] = f2bf(v0); hcur_bf[p1] = f2bf(v1);
            }
        }
    }
}

// ---------------- host side ----------------
extern "C" void kernel_launch(void* const* d_in, const int* in_sizes, int n_in,
                              void* d_out, int out_size, void* d_ws, size_t ws_size,
                              hipStream_t stream) {
    const float* h   = (const float*)d_in[0];
    const int*   adj = (const int*)d_in[1];
    const float* z   = (const float*)d_in[2];
    const float* Wp  = (const float*)d_in[3];
    const float* bp  = (const float*)d_in[4];
    const float* Wm  = (const float*)d_in[5];
    const float* bm  = (const float*)d_in[6];
    const float* Wg  = (const float*)d_in[7];
    const float* bg  = (const float*)d_in[8];
    const float* Wk  = (const float*)d_in[9];
    const float* bk  = (const float*)d_in[10];
    const float* Wq  = (const float*)d_in[11];
    const float* bq  = (const float*)d_in[12];
    const float* a   = (const float*)d_in[13];
    float* out = (float*)d_out;

    uint8_t* ws = (uint8_t*)d_ws;
    size_t cur = 0;
    auto alloc = [&](size_t bytes) -> uint8_t* {
        uint8_t* p = ws + cur;
        cur = (cur + bytes + 255) & ~(size_t)255;
        return p;
    };
    uint32_t* maskw  = (uint32_t*)alloc((size_t)cN * 128 * 4);
    uint32_t* maskT  = (uint32_t*)alloc((size_t)cN * 128 * 4);
    float*    h_f32  = (float*)   alloc((size_t)cN * 256 * 4);
    uint16_t* hin_bf = (uint16_t*)alloc((size_t)cN * 256 * 2);
    uint16_t* hcur   = (uint16_t*)alloc((size_t)cN * 256 * 2);
    uint16_t* z_bf   = (uint16_t*)alloc((size_t)cN * 128 * 2);
    uint16_t* WpT    = (uint16_t*)alloc(65536 * 2);
    uint16_t* WmT    = (uint16_t*)alloc((size_t)cL * 65536 * 2);
    uint16_t* WgT    = (uint16_t*)alloc((size_t)cL * 98304 * 2);
    uint16_t* gmT    = (uint16_t*)alloc((size_t)cN * 256 * 2);
    float*    wqv    = (float*)   alloc(cL * 256 * 4);
    float*    wkv    = (float*)   alloc(cL * 256 * 4);
    float*    cvec   = (float*)   alloc(256);
    float*    qqp    = (float*)   alloc(8ull * cN * 4);
    float*    kk     = (float*)   alloc(cN * 4);
    float2*   stats2 = (float2*)  alloc(cN * 8);
    float*    gsum   = (float*)   alloc(256);
    uint32_t* donecnt= (uint32_t*)alloc(128 * 4);
    uint32_t* part   = (uint32_t*)alloc(8ull * cN * 256 * 2);
    (void)cur;

    // 1024 (h) + 512 (z) + 16 (Wp) + 32 (Wm) + 48 (Wg) + 16 (wvec) + 1024 (bits) = 2672 blocks
    k_prep<<<2672, 256, 0, stream>>>(h, z, Wp, Wm, Wg, Wq, bq, Wk, bk, a, adj,
                                     hin_bf, z_bf, WpT, WmT, WgT, wqv, wkv, cvec, maskw, gsum, donecnt);
    // 256 (bitsT) + 256 (proj) = 512 blocks
    k_pt<<<512, 256, 0, stream>>>(maskw, maskT, hin_bf, WpT, bp, h_f32, hcur);

    for (int l = 0; l < cL; ++l) {
        k_msgg<<<dim3(64, 4), 256, 0, stream>>>(hcur, z_bf, WmT, WgT, bm, bg,
                                                wqv, wkv, cvec, gmT, qqp, kk, gsum, l);
        k_stats<<<cN / 4, 256, 0, stream>>>(qqp, kk, maskw, stats2);
        k_agg<<<dim3(64, 8), 512, 0, stream>>>(gmT, stats2, maskT, kk, part,
                                               h_f32, hcur, out, gsum, donecnt, l == cL - 1 ? 1 : 0);
    }
}

// Round 17
// 135.796 us; speedup vs baseline: 2.7617x; 2.6929x over previous
//
#include <hip/hip_runtime.h>
#include <hip/hip_bf16.h>
#include <stdint.h>

static constexpr int cN    = 4096;
static constexpr int cHID  = 256;
static constexpr int cTASK = 128;
static constexpr int cL    = 2;
static constexpr float RLN2 = 1.4426950408889634f;   // 1/ln2

typedef short bf16x8 __attribute__((ext_vector_type(8)));
typedef float f32x4  __attribute__((ext_vector_type(4)));

#define MFMA(a, b, c) __builtin_amdgcn_mfma_f32_16x16x32_bf16((a), (b), (c), 0, 0, 0)

static __device__ __forceinline__ uint16_t f2bf(float f) {
    uint32_t u = __float_as_uint(f);
    uint32_t r = (u + 0x7FFFu + ((u >> 16) & 1u)) >> 16;
    return (uint16_t)r;
}
static __device__ __forceinline__ float bf2f(uint16_t h) {
    return __uint_as_float(((uint32_t)h) << 16);
}
static __device__ __forceinline__ bf16x8 ld_frag(const uint16_t* p) {
    return *reinterpret_cast<const bf16x8*>(p);
}
static __device__ __forceinline__ uint32_t pkf16(float a, float b) {
    _Float16 ha = (_Float16)a, hb = (_Float16)b;
    uint16_t ua, ub;
    __builtin_memcpy(&ua, &ha, 2);
    __builtin_memcpy(&ub, &hb, 2);
    return (uint32_t)ua | ((uint32_t)ub << 16);
}
static __device__ __forceinline__ float f16lo(uint32_t v) {
    uint16_t u = (uint16_t)(v & 0xFFFFu); _Float16 h;
    __builtin_memcpy(&h, &u, 2); return (float)h;
}
static __device__ __forceinline__ float f16hi(uint32_t v) {
    uint16_t u = (uint16_t)(v >> 16); _Float16 h;
    __builtin_memcpy(&h, &u, 2); return (float)h;
}
static __device__ __forceinline__ uint32_t spread4(uint32_t x) {
    x = (x | (x << 12)) & 0x000F000Fu;
    x = (x | (x << 6))  & 0x03030303u;
    x = (x | (x << 3))  & 0x11111111u;
    return x;
}
// async global->LDS, 16B per lane; LDS dest is wave-uniform base + lane*16
static __device__ __forceinline__ void gload_lds16(const void* g, void* l) {
    __builtin_amdgcn_global_load_lds((const __attribute__((address_space(1))) void*)g,
                                     (__attribute__((address_space(3))) void*)l, 16, 0, 0);
}

// ---------------- merged prep: casts + weight transposes + wvec + adj bitmask ----------------
static __device__ __forceinline__ void castT_body(const float* __restrict__ S,
                                                  uint16_t* __restrict__ D, int K, int bx,
                                                  uint16_t (*t)[72]) {
    int ntk = K / 64;
    int tk = (bx % ntk) * 64;
    int td = (bx / ntk) * 64;
    int lane = threadIdx.x & 63, w = threadIdx.x >> 6;
    for (int r = w; r < 64; r += 4) t[r][lane] = f2bf(S[(size_t)(tk + r) * 256 + td + lane]);
    __syncthreads();
    for (int r = w; r < 64; r += 4) D[(size_t)(td + r) * K + tk + lane] = t[lane][r];
}

__global__ __launch_bounds__(256) void k_prep(const float* __restrict__ h,
                                              const float* __restrict__ z,
                                              const float* __restrict__ Wp,
                                              const float* __restrict__ Wm,
                                              const float* __restrict__ Wg,
                                              const float* __restrict__ Wq,
                                              const float* __restrict__ bq,
                                              const float* __restrict__ Wk,
                                              const float* __restrict__ bk,
                                              const float* __restrict__ a,
                                              const int* __restrict__ adj,
                                              uint16_t* __restrict__ hin_bf,
                                              uint16_t* __restrict__ z_bf,
                                              uint16_t* __restrict__ WpT,
                                              uint16_t* __restrict__ WmT,
                                              uint16_t* __restrict__ WgT,
                                              float* __restrict__ wqv,
                                              float* __restrict__ wkv,
                                              float* __restrict__ cvec,
                                              uint32_t* __restrict__ maskw,
                                              float* __restrict__ gsum) {
    __shared__ uint16_t sht[64][72];
    __shared__ float shf[2][256];
    int b = blockIdx.x, tid = threadIdx.x;
    if (b == 0 && tid == 0) gsum[0] = 0.f;
    if (b < 1024) {                                    // h cast (vec4)
        int idx = b * 256 + tid;
        float4 v = reinterpret_cast<const float4*>(h)[idx];
        ushort4 o; o.x = f2bf(v.x); o.y = f2bf(v.y); o.z = f2bf(v.z); o.w = f2bf(v.w);
        reinterpret_cast<ushort4*>(hin_bf)[idx] = o;
        return;
    }
    b -= 1024;
    if (b < 512) {                                     // z cast (vec4)
        int idx = b * 256 + tid;
        float4 v = reinterpret_cast<const float4*>(z)[idx];
        ushort4 o; o.x = f2bf(v.x); o.y = f2bf(v.y); o.z = f2bf(v.z); o.w = f2bf(v.w);
        reinterpret_cast<ushort4*>(z_bf)[idx] = o;
        return;
    }
    b -= 512;
    if (b < 16) { castT_body(Wp, WpT, 256, b, sht); return; }
    b -= 16;
    if (b < 32) { castT_body(Wm + (b >> 4) * 65536, WmT + (b >> 4) * 65536, 256, b & 15, sht); return; }
    b -= 32;
    if (b < 48) { castT_body(Wg + (b / 24) * 98304, WgT + (b / 24) * 98304, 384, b % 24, sht); return; }
    b -= 48;
    if (b < 16) {   // wvec: l = b>>3, which = (b>>2)&1, q = b&3  (results scaled by 1/ln2)
        int l = b >> 3, which = (b >> 2) & 1, q = b & 3;
        int lane = tid & 63, wid = tid >> 6;
        const float* W    = which ? (Wk + l * 65536) : (Wq + l * 65536);
        const float* avec = a + l * 512 + (which ? 0 : 256);
        float* av = shf[0];
        float* red = shf[1];
        av[tid] = avec[tid];
        __syncthreads();
        float av0 = av[lane], av1 = av[64 + lane], av2 = av[128 + lane], av3 = av[192 + lane];
        float* wv = which ? wkv : wqv;
        for (int dd = 0; dd < 16; ++dd) {
            int d = q * 64 + wid * 16 + dd;
            const float* Wr = W + (size_t)d * 256;
            float s = Wr[lane] * av0 + Wr[64 + lane] * av1 + Wr[128 + lane] * av2 + Wr[192 + lane] * av3;
            for (int off = 32; off; off >>= 1) s += __shfl_down(s, off, 64);
            if (lane == 0) wv[l * 256 + d] = s * RLN2;
        }
        if (q == 0) {
            const float* bias = which ? (bk + l * 256) : (bq + l * 256);
            red[tid] = bias[tid] * av[tid];
            __syncthreads();
            for (int off = 128; off; off >>= 1) {
                if (tid < off) red[tid] += red[tid + off];
                __syncthreads();
            }
            if (tid == 0) cvec[l * 2 + which] = red[0] * RLN2;
        }
        return;
    }
    b -= 16;
    {   // adj -> bitmask: 1024 blocks, 4 rows each
        int wid = tid >> 6, lane = tid & 63;
        int i = b * 4 + wid;
        const int* row = adj + (size_t)i * cN;
        uint32_t* orow = maskw + (size_t)i * 128;
        for (int ch = 0; ch < 16; ++ch) {
            int4 v = reinterpret_cast<const int4*>(row + ch * 256)[lane];
            uint64_t b0 = __ballot(v.x > 0);
            uint64_t b1 = __ballot(v.y > 0);
            uint64_t b2 = __ballot(v.z > 0);
            uint64_t b3 = __ballot(v.w > 0);
            int k = lane & 7;
            uint32_t e0 = spread4((uint32_t)(b0 >> (8 * k)) & 0xFFu);
            uint32_t e1 = spread4((uint32_t)(b1 >> (8 * k)) & 0xFFu);
            uint32_t e2 = spread4((uint32_t)(b2 >> (8 * k)) & 0xFFu);
            uint32_t e3 = spread4((uint32_t)(b3 >> (8 * k)) & 0xFFu);
            if (lane < 8) orow[ch * 8 + k] = e0 | (e1 << 1) | (e2 << 2) | (e3 << 3);
        }
    }
}

// ---------------- merged: mask bit-transpose (blocks 0-255) + initial projection (blocks 256-511) ----------------
__global__ __launch_bounds__(256) void k_pt(const uint32_t* __restrict__ maskw,
                                            uint32_t* __restrict__ maskT,
                                            const uint16_t* __restrict__ hin_bf,
                                            const uint16_t* __restrict__ WpT,
                                            const float* __restrict__ bp,
                                            float* __restrict__ h_f32,
                                            uint16_t* __restrict__ hcur_bf) {
    __shared__ uint32_t ml[256][9];
    int tid = threadIdx.x;
    if (blockIdx.x < 256) {   // ---- bit-transpose ----
        int bi = blockIdx.x & 15, bj = blockIdx.x >> 4;
        int i0 = bi * 256, j0 = bj * 256;
        {
            const uint32_t* src = maskw + (size_t)(i0 + tid) * 128 + bj * 8;
            uint4 a = *reinterpret_cast<const uint4*>(src);
            uint4 b = *reinterpret_cast<const uint4*>(src + 4);
            ml[tid][0] = a.x; ml[tid][1] = a.y; ml[tid][2] = a.z; ml[tid][3] = a.w;
            ml[tid][4] = b.x; ml[tid][5] = b.y; ml[tid][6] = b.z; ml[tid][7] = b.w;
        }
        __syncthreads();
        int lane = tid & 63, wid = tid >> 6;
        int tw = wid * 2 + (lane >> 5);
        int l31 = lane & 31;
        uint32_t ow[8];
#pragma unroll
        for (int ti = 0; ti < 8; ++ti) {
            uint32_t m = ml[ti * 32 + l31][tw];
            uint32_t myw = 0;
#pragma unroll
            for (int c = 0; c < 32; ++c) {
                uint64_t bl = __ballot(((m >> c) & 1) != 0);
                uint32_t v = (lane < 32) ? (uint32_t)bl : (uint32_t)(bl >> 32);
                if (l31 == c) myw = v;
            }
            ow[ti] = myw;
        }
        uint32_t* dst = maskT + (size_t)(j0 + tw * 32 + l31) * 128 + bi * 8;
        *reinterpret_cast<uint4*>(dst)     = make_uint4(ow[0], ow[1], ow[2], ow[3]);
        *reinterpret_cast<uint4*>(dst + 4) = make_uint4(ow[4], ow[5], ow[6], ow[7]);
        return;
    }
    // ---- initial projection: h = hin @ Wp + bp ----
    int bb = blockIdx.x - 256;
    int bx = bb & 63, by = bb >> 6;
    int lane = tid & 63, wid = tid >> 6;
    int wr = wid >> 1, wc = wid & 1;
    int l16 = lane & 15, g = lane >> 4;
    int i0 = bx * 64 + wr * 32, d0 = by * 64 + wc * 32;
    f32x4 acc[2][2] = {};
#pragma unroll
    for (int ks = 0; ks < 8; ++ks) {
        int kb = ks * 32 + g * 8;
        bf16x8 afr[2], bfr[2];
#pragma unroll
        for (int mr = 0; mr < 2; ++mr) afr[mr] = ld_frag(hin_bf + (size_t)(i0 + mr * 16 + l16) * 256 + kb);
#pragma unroll
        for (int nr = 0; nr < 2; ++nr) bfr[nr] = ld_frag(WpT + (size_t)(d0 + nr * 16 + l16) * 256 + kb);
#pragma unroll
        for (int mr = 0; mr < 2; ++mr)
#pragma unroll
            for (int nr = 0; nr < 2; ++nr)
                acc[mr][nr] = MFMA(afr[mr], bfr[nr], acc[mr][nr]);
    }
#pragma unroll
    for (int mr = 0; mr < 2; ++mr)
#pragma unroll
        for (int nr = 0; nr < 2; ++nr) {
            int d = d0 + nr * 16 + l16;
            float bias = bp[d];
#pragma unroll
            for (int r = 0; r < 4; ++r) {
                int i = i0 + mr * 16 + g * 4 + r;
                float v = acc[mr][nr][r] + bias;
                h_f32[(size_t)i * 256 + d] = v;
                hcur_bf[(size_t)i * 256 + d] = f2bf(v);
            }
        }
}

// ---------------- fused message+gate GEMM + kk GEMV + qq partials + gate L1; writes gmT ----------------
__global__ __launch_bounds__(256) void k_msgg(const uint16_t* __restrict__ hcur_bf,
                                              const uint16_t* __restrict__ z_bf,
                                              const uint16_t* __restrict__ WmT,
                                              const uint16_t* __restrict__ WgT,
                                              const float* __restrict__ bm,
                                              const float* __restrict__ bg,
                                              const float* __restrict__ wqv,
                                              const float* __restrict__ wkv,
                                              const float* __restrict__ cvec,
                                              uint16_t* __restrict__ gmT,
                                              float* __restrict__ qqp,
                                              float* __restrict__ kkv,
                                              float* __restrict__ gsum,
                                              int layer) {
    __shared__ float wkv_s[256], wqv_s[256];
    __shared__ float wred[4];
    int tid = threadIdx.x;
    wkv_s[tid] = wkv[layer * 256 + tid];
    wqv_s[tid] = wqv[layer * 256 + tid];
    __syncthreads();

    int bx = blockIdx.x, by = blockIdx.y;
    int lane = tid & 63, wid = tid >> 6;
    int wr = wid >> 1, wc = wid & 1;
    int l16 = lane & 15, g = lane >> 4;
    int i0 = bx * 64 + wr * 32, d0 = by * 64 + wc * 32;
    bool doKK = (by == 0);
    const uint16_t* WmTl = WmT + layer * 65536;
    const uint16_t* WgTl = WgT + layer * 98304;
    f32x4 am[2][2] = {}, ag[2][2] = {};
    float kkp[2] = {0.f, 0.f};
#pragma unroll
    for (int ks = 0; ks < 8; ++ks) {
        int kb = ks * 32 + g * 8;
        bf16x8 afr[2], bmf[2], bgf[2];
#pragma unroll
        for (int mr = 0; mr < 2; ++mr) afr[mr] = ld_frag(hcur_bf + (size_t)(i0 + mr * 16 + l16) * 256 + kb);
#pragma unroll
        for (int nr = 0; nr < 2; ++nr) {
            bmf[nr] = ld_frag(WmTl + (size_t)(d0 + nr * 16 + l16) * 256 + kb);
            bgf[nr] = ld_frag(WgTl + (size_t)(d0 + nr * 16 + l16) * 384 + kb);
        }
        if (doKK) {
#pragma unroll
            for (int mr = 0; mr < 2; ++mr)
#pragma unroll
                for (int u = 0; u < 8; ++u)
                    kkp[mr] += bf2f((uint16_t)afr[mr][u]) * wkv_s[kb + u];
        }
#pragma unroll
        for (int mr = 0; mr < 2; ++mr)
#pragma unroll
            for (int nr = 0; nr < 2; ++nr) {
                am[mr][nr] = MFMA(afr[mr], bmf[nr], am[mr][nr]);
                ag[mr][nr] = MFMA(afr[mr], bgf[nr], ag[mr][nr]);
            }
    }
#pragma unroll
    for (int ks = 0; ks < 4; ++ks) {   // z part of concat: k = 256..383
        int kb = ks * 32 + g * 8;
        bf16x8 afr[2], bgf[2];
#pragma unroll
        for (int mr = 0; mr < 2; ++mr) afr[mr] = ld_frag(z_bf + (size_t)(i0 + mr * 16 + l16) * 128 + kb);
#pragma unroll
        for (int nr = 0; nr < 2; ++nr) bgf[nr] = ld_frag(WgTl + (size_t)(d0 + nr * 16 + l16) * 384 + 256 + kb);
#pragma unroll
        for (int mr = 0; mr < 2; ++mr)
#pragma unroll
            for (int nr = 0; nr < 2; ++nr)
                ag[mr][nr] = MFMA(afr[mr], bgf[nr], ag[mr][nr]);
    }
    float gs = 0.f;
    float qqt[2][4] = {};
#pragma unroll
    for (int mr = 0; mr < 2; ++mr)
#pragma unroll
        for (int nr = 0; nr < 2; ++nr) {
            int d = d0 + nr * 16 + l16;
            float bmv = bm[layer * 256 + d], bgv = bg[layer * 256 + d];
            float wqd = wqv_s[d];
            ushort4 pack;
#pragma unroll
            for (int r = 0; r < 4; ++r) {
                float rm = am[mr][nr][r] + bmv; rm = rm > 0.f ? rm : 0.f;
                float gt = 1.f / (1.f + __expf(-(ag[mr][nr][r] + bgv)));
                gs += gt;
                float gmv = gt * rm;
                qqt[mr][r] += gmv * wqd;
                ((uint16_t*)&pack)[r] = f2bf(gmv);
            }
            int i = i0 + mr * 16 + g * 4;
            *reinterpret_cast<ushort4*>(gmT + (size_t)d * cN + i) = pack;
        }
    // deterministic qq partials: slot = by*2 + wc
#pragma unroll
    for (int mr = 0; mr < 2; ++mr)
#pragma unroll
        for (int r = 0; r < 4; ++r) {
            float v = qqt[mr][r];
            v += __shfl_xor(v, 1, 64);
            v += __shfl_xor(v, 2, 64);
            v += __shfl_xor(v, 4, 64);
            v += __shfl_xor(v, 8, 64);
            if (l16 == 0) qqp[(size_t)(by * 2 + wc) * cN + i0 + mr * 16 + g * 4 + r] = v;
        }
    if (doKK) {
        float cc = cvec[layer * 2 + 0] + cvec[layer * 2 + 1];
#pragma unroll
        for (int mr = 0; mr < 2; ++mr) {
            float v = kkp[mr];
            v += __shfl_xor(v, 16, 64);
            v += __shfl_xor(v, 32, 64);
            if (lane < 16) kkv[i0 + mr * 16 + l16] = v + cc;
        }
    }
    for (int off = 32; off; off >>= 1) gs += __shfl_down(gs, off, 64);
    if (lane == 0) wred[wid] = gs;
    __syncthreads();
    if (tid == 0) atomicAdd(gsum, wred[0] + wred[1] + wred[2] + wred[3]);
}

// ---------------- per-row: qq = sum of 8 partials ; den = sum_masked exp2(lrelu') ----------------
__global__ __launch_bounds__(256) void k_stats(const float* __restrict__ qqp,
                                               const float* __restrict__ kkv,
                                               const uint32_t* __restrict__ maskw,
                                               float2* __restrict__ stats2) {
    int wid = threadIdx.x >> 6, lane = threadIdx.x & 63;
    int i = blockIdx.x * 4 + wid;
    float qq = 0.f;
#pragma unroll
    for (int s = 0; s < 8; ++s) qq += qqp[(size_t)s * cN + i];
    const uint32_t* mrow = maskw + (size_t)i * 128;
    float den = 0.f;
#pragma unroll 4
    for (int c = 0; c < 64; ++c) {
        int j = c * 64 + lane;
        uint32_t w = mrow[j >> 5];
        bool on = (w >> (j & 31)) & 1;
        float e = qq + kkv[j];
        e = fmaxf(e, 0.01f * e);
        e = fminf(e, 80.f);
        den += on ? exp2f(e) : 0.f;
    }
#pragma unroll
    for (int off = 32; off; off >>= 1) den += __shfl_xor(den, off, 64);
    if (lane == 0) stats2[i] = make_float2(qq, den > 0.f ? 1.f / den : 0.f);
}

// ---------------- agg = attention^T @ gm : async gload_lds B staging (pre-swizzled source), dbuf ----------------
// grid (64 jb, 8 seg), 512 thr = 8 waves: wave = (jg=wid>>2) 32 j x (dg=wid&3) 64 d.
// B LDS [256 d][64 i] dbuf; LDS image identical to r9's swizzled layout via pre-swizzled GLOBAL source.
__global__ __launch_bounds__(512, 4) void k_agg(const uint16_t* __restrict__ gmT,
                                                const float2* __restrict__ stats2,
                                                const uint32_t* __restrict__ maskT,
                                                const float* __restrict__ kkv,
                                                uint32_t* __restrict__ part) {
    __shared__ uint16_t B_lds[2][256 * 64];            // 2 x 32 KiB
    __shared__ uint16_t A_lds[2][64 * 64];             // 2 x 8 KiB
    int jb = blockIdx.x, seg = blockIdx.y;
    int tid = threadIdx.x, lane = tid & 63, wid = tid >> 6;
    int l16 = lane & 15, g = lane >> 4;
    int jg = wid >> 2, dg = wid & 3;
    int jt = jb * 64;
    int ib0 = seg * 512;
    f32x4 acc[2][4] = {};

    // ---- B staging via async global_load_lds: wave wid covers d-rows [wid*32, wid*32+32)
    // LDS linear dest (base + lane*16); swizzle moved to source: i-offset = 8*((lane&7)^(lane>>3))
    int io8 = 8 * ((lane & 7) ^ (lane >> 3));
    const uint16_t* gsrc0 = gmT + (size_t)(wid * 32 + (lane >> 3)) * cN + ib0 + io8;
    auto stageB = [&](int buf, int stg) {
        const uint16_t* gs = gsrc0 + stg * 64;
        uint16_t* ldst = &B_lds[buf][(wid * 32) * 64];
#pragma unroll
        for (int c = 0; c < 4; ++c)
            gload_lds16(gs + (size_t)(c * 8) * cN, ldst + (c * 8) * 64);
    };
    // ---- A compute: thread -> j = tid>>3 (0..63), i-octet io = tid&7 (8 i each)
    int at_j = tid >> 3, at_io = tid & 7;
    float kk_t = kkv[jt + at_j];
    const uint32_t* mrow_t = maskT + (size_t)(jt + at_j) * 128;
    int ash = (at_io * 16) ^ ((at_j & 7) << 4);
    uint8_t* arow[2] = { reinterpret_cast<uint8_t*>(&A_lds[0][0]) + at_j * 128 + ash,
                         reinterpret_cast<uint8_t*>(&A_lds[1][0]) + at_j * 128 + ash };
    auto stageA = [&](int buf, int stg) {
        int ib = ib0 + stg * 64 + at_io * 8;
        uint32_t mword = mrow_t[ib >> 5];
        int shift = ib & 31;
        const float2* sp = stats2 + ib;
        union { bf16x8 v; uint16_t s[8]; } aw;
#pragma unroll
        for (int u = 0; u < 8; ++u) {
            float2 st = sp[u];
            float e = st.x + kk_t;
            e = fmaxf(e, 0.01f * e);
            e = fminf(e, 80.f);
            float w = exp2f(e) * st.y;
            aw.s[u] = ((mword >> (shift + u)) & 1) ? f2bf(w) : (uint16_t)0;
        }
        *reinterpret_cast<bf16x8*>(arow[buf]) = aw.v;
    };

    stageB(0, 0);
    stageA(0, 0);
    __syncthreads();
    int rxor = (l16 & 7) << 4;

    for (int stg = 0; stg < 8; ++stg) {
        if (stg < 7) {                                 // async B + A-exp for next stage into alt buffers
            stageB((stg + 1) & 1, stg + 1);
            stageA((stg + 1) & 1, stg + 1);
        }
        const uint8_t* cb = reinterpret_cast<const uint8_t*>(&B_lds[stg & 1][0]);
        const uint8_t* ca = reinterpret_cast<const uint8_t*>(&A_lds[stg & 1][0]);
#pragma unroll
        for (int k = 0; k < 2; ++k) {
            int cofs = (k * 64 + g * 16);
            bf16x8 a0 = *reinterpret_cast<const bf16x8*>(ca + (size_t)(jg * 32 + l16) * 128 + (cofs ^ rxor));
            bf16x8 a1 = *reinterpret_cast<const bf16x8*>(ca + (size_t)(jg * 32 + 16 + l16) * 128 + (cofs ^ rxor));
            const uint8_t* bcol = cb + (size_t)(dg * 64 + l16) * 128 + (cofs ^ rxor);
#pragma unroll
            for (int nf = 0; nf < 4; ++nf) {
                bf16x8 bfr = *reinterpret_cast<const bf16x8*>(bcol + nf * (16 * 128));
                acc[0][nf] = MFMA(a0, bfr, acc[0][nf]);
                acc[1][nf] = MFMA(a1, bfr, acc[1][nf]);
            }
        }
        __syncthreads();                               // drains vmcnt (async B) + lgkm; alt ready for next stage
    }
    // coalesced part write: [seg][jb][wid][mf][nf][rr][lane] u32 (f16 pair r=2rr,2rr+1)
    uint32_t* pb = part + ((size_t)(seg * 64 + jb) * 8 + wid) * 1024;
#pragma unroll
    for (int mf = 0; mf < 2; ++mf)
#pragma unroll
        for (int nf = 0; nf < 4; ++nf)
#pragma unroll
            for (int rr = 0; rr < 2; ++rr)
                pb[(((mf * 4 + nf) * 2) + rr) * 64 + lane] =
                    pkf16(acc[mf][nf][rr * 2], acc[mf][nf][rr * 2 + 1]);
}

// ---------------- residual: h = (sum of 8 f16 parts + h)/2 ; decodes k_agg's wave layout ----------------
__global__ __launch_bounds__(256) void k_resid(const uint32_t* __restrict__ part,
                                               float* __restrict__ h_f32,
                                               uint16_t* __restrict__ hcur_bf,
                                               float* __restrict__ out,
                                               const float* __restrict__ gsum,
                                               int last) {
    int jb = blockIdx.x >> 3, wid = blockIdx.x & 7;    // 512 blocks: (64 jb, 8 wid)
    int tid = threadIdx.x;
    int jg = wid >> 2, dg = wid & 3;
    if (last && blockIdx.x == 0 && tid == 0)
        out[(size_t)cN * cHID] = gsum[0] * (1.f / ((float)(cN * cHID) * (float)cL));
    const uint32_t* pb = part + ((size_t)jb * 8 + wid) * 1024;
#pragma unroll
    for (int t = 0; t < 4; ++t) {
        int idx = t * 256 + tid;
        float s0 = 0.f, s1 = 0.f;
#pragma unroll
        for (int seg = 0; seg < 8; ++seg) {
            uint32_t v = pb[(size_t)seg * (64 * 8 * 1024) + idx];
            s0 += f16lo(v); s1 += f16hi(v);
        }
        int mf = idx >> 9, nf = (idx >> 7) & 3, rr = (idx >> 6) & 1, lane = idx & 63;
        int j = jb * 64 + jg * 32 + mf * 16 + (lane >> 4) * 4 + rr * 2;
        int d = dg * 64 + nf * 16 + (lane & 15);
        size_t i0 = (size_t)j * 256 + d, i1 = i0 + 256;
        float v0 = (s0 + h_f32[i0]) * 0.5f;
        float v1 = (s1 + h_f32[i1]) * 0.5f;
        if (last) {
            out[i0] = v0; out[i1] = v1;
        } else {
            h_f32[i0] = v0; h_f32[i1] = v1;
            hcur_bf[i0] = f2bf(v0); hcur_bf[i1] = f2bf(v1);
        }
    }
}

// ---------------- host side ----------------
extern "C" void kernel_launch(void* const* d_in, const int* in_sizes, int n_in,
                              void* d_out, int out_size, void* d_ws, size_t ws_size,
                              hipStream_t stream) {
    const float* h   = (const float*)d_in[0];
    const int*   adj = (const int*)d_in[1];
    const float* z   = (const float*)d_in[2];
    const float* Wp  = (const float*)d_in[3];
    const float* bp  = (const float*)d_in[4];
    const float* Wm  = (const float*)d_in[5];
    const float* bm  = (const float*)d_in[6];
    const float* Wg  = (const float*)d_in[7];
    const float* bg  = (const float*)d_in[8];
    const float* Wk  = (const float*)d_in[9];
    const float* bk  = (const float*)d_in[10];
    const float* Wq  = (const float*)d_in[11];
    const float* bq  = (const float*)d_in[12];
    const float* a   = (const float*)d_in[13];
    float* out = (float*)d_out;

    uint8_t* ws = (uint8_t*)d_ws;
    size_t cur = 0;
    auto alloc = [&](size_t bytes) -> uint8_t* {
        uint8_t* p = ws + cur;
        cur = (cur + bytes + 255) & ~(size_t)255;
        return p;
    };
    uint32_t* maskw  = (uint32_t*)alloc((size_t)cN * 128 * 4);
    uint32_t* maskT  = (uint32_t*)alloc((size_t)cN * 128 * 4);
    float*    h_f32  = (float*)   alloc((size_t)cN * 256 * 4);
    uint16_t* hin_bf = (uint16_t*)alloc((size_t)cN * 256 * 2);
    uint16_t* hcur   = (uint16_t*)alloc((size_t)cN * 256 * 2);
    uint16_t* z_bf   = (uint16_t*)alloc((size_t)cN * 128 * 2);
    uint16_t* WpT    = (uint16_t*)alloc(65536 * 2);
    uint16_t* WmT    = (uint16_t*)alloc((size_t)cL * 65536 * 2);
    uint16_t* WgT    = (uint16_t*)alloc((size_t)cL * 98304 * 2);
    uint16_t* gmT    = (uint16_t*)alloc((size_t)cN * 256 * 2);
    float*    wqv    = (float*)   alloc(cL * 256 * 4);
    float*    wkv    = (float*)   alloc(cL * 256 * 4);
    float*    cvec   = (float*)   alloc(256);
    float*    qqp    = (float*)   alloc(8ull * cN * 4);
    float*    kk     = (float*)   alloc(cN * 4);
    float2*   stats2 = (float2*)  alloc(cN * 8);
    float*    gsum   = (float*)   alloc(256);
    uint32_t* part   = (uint32_t*)alloc(8ull * cN * 256 * 2);
    (void)cur;

    // 1024 (h) + 512 (z) + 16 (Wp) + 32 (Wm) + 48 (Wg) + 16 (wvec) + 1024 (bits) = 2672 blocks
    k_prep<<<2672, 256, 0, stream>>>(h, z, Wp, Wm, Wg, Wq, bq, Wk, bk, a, adj,
                                     hin_bf, z_bf, WpT, WmT, WgT, wqv, wkv, cvec, maskw, gsum);
    // 256 (bitsT) + 256 (proj) = 512 blocks
    k_pt<<<512, 256, 0, stream>>>(maskw, maskT, hin_bf, WpT, bp, h_f32, hcur);

    for (int l = 0; l < cL; ++l) {
        k_msgg<<<dim3(64, 4), 256, 0, stream>>>(hcur, z_bf, WmT, WgT, bm, bg,
                                                wqv, wkv, cvec, gmT, qqp, kk, gsum, l);
        k_stats<<<cN / 4, 256, 0, stream>>>(qqp, kk, maskw, stats2);
        k_agg<<<dim3(64, 8), 512, 0, stream>>>(gmT, stats2, maskT, kk, part);
        k_resid<<<512, 256, 0, stream>>>(part, h_f32, hcur, out, gsum, l == cL - 1 ? 1 : 0);
    }
}